// Round 1
// baseline (826.790 us; speedup 1.0000x reference)
//
#include <hip/hip_runtime.h>
#include <math.h>

#define C 128
#define SEGS 48
#define BLK 256

__device__ __forceinline__ float4 f4add(float4 a, float4 b) {
    float4 r; r.x = a.x + b.x; r.y = a.y + b.y; r.z = a.z + b.z; r.w = a.w + b.w; return r;
}

__device__ __forceinline__ float4 f4shfl_xor(float4 v, int m) {
    float4 r;
    r.x = __shfl_xor(v.x, m, 64);
    r.y = __shfl_xor(v.y, m, 64);
    r.z = __shfl_xor(v.z, m, 64);
    r.w = __shfl_xor(v.w, m, 64);
    return r;
}

extern "C" __global__ __launch_bounds__(BLK, 2)
void cba_fused_kernel(const float* __restrict__ x,
                      const float* __restrict__ W,
                      const int* __restrict__ batch,
                      float* __restrict__ out,
                      int N, int B)
{
    __shared__ float  sW[C * C];        // 64 KB: weight_c, row-major [k][col]
    __shared__ int    sStart[SEGS + 1]; // segment boundaries
    __shared__ float4 sRed[128];        // 2 KB reduction buffer
    __shared__ float  sMean[C];
    __shared__ float  sC[C];

    const int t    = threadIdx.x;   // 0..255
    const int lane = t & 63;
    const int wave = t >> 6;        // 0..3
    const int rg   = t >> 5;        // row-group / k-chunk, 0..7
    const int lp   = t & 31;        // position within 32-lane group

    // ---- load W into LDS (coalesced float4) ----
    const float4* Wg  = (const float4*)W;
    float4*       sW4 = (float4*)sW;
#pragma unroll
    for (int i = 0; i < 16; ++i)
        sW4[t + i * BLK] = Wg[t + i * BLK];

    // ---- segment boundaries for this block via parallel binary search ----
    const int b0   = blockIdx.x * SEGS;
    const int nseg = min(SEGS, B - b0);
    if (t <= nseg) {
        const int target = b0 + t;
        int lo = 0, hi = N;
        while (lo < hi) {                 // lower_bound: first idx with batch[idx] >= target
            int mid = (lo + hi) >> 1;
            if (batch[mid] < target) lo = mid + 1; else hi = mid;
        }
        sStart[t] = lo;
    }
    __syncthreads();

    const float4* x4 = (const float4*)x;

    for (int sb = 0; sb < nseg; ++sb) {
        const int b   = b0 + sb;
        const int s   = sStart[sb];
        const int e   = sStart[sb + 1];
        const int cnt = e - s;

        // ---- pass 1: per-channel segment sums (8 rows in flight, float4/lane) ----
        float4 acc = {0.f, 0.f, 0.f, 0.f};
        for (int i = s + rg; i < e; i += 8) {
            float4 v = x4[(size_t)i * 32 + lp];
            acc.x += v.x; acc.y += v.y; acc.z += v.z; acc.w += v.w;
        }
        acc = f4add(acc, f4shfl_xor(acc, 32));       // combine row-group pairs within wave
        if (lane < 32) sRed[wave * 32 + lp] = acc;
        __syncthreads();
        if (t < 32) {
            float4 ssum = f4add(f4add(sRed[t], sRed[32 + t]),
                                f4add(sRed[64 + t], sRed[96 + t]));
            const float inv = 1.0f / (float)(cnt > 0 ? cnt : 1);
            sMean[4 * t + 0] = ssum.x * inv;
            sMean[4 * t + 1] = ssum.y * inv;
            sMean[4 * t + 2] = ssum.z * inv;
            sMean[4 * t + 3] = ssum.w * inv;
        }
        __syncthreads();

        // ---- c = tanh(mean @ W): thread t does cols 4*lp..+3, k-chunk rg*16..+15 ----
        float4 p = {0.f, 0.f, 0.f, 0.f};
#pragma unroll
        for (int kk = 0; kk < 16; ++kk) {
            const int k = rg * 16 + kk;
            const float m  = sMean[k];               // broadcast read
            const float4 w = sW4[k * 32 + lp];       // 16 B/lane, conflict-free
            p.x = fmaf(m, w.x, p.x);
            p.y = fmaf(m, w.y, p.y);
            p.z = fmaf(m, w.z, p.z);
            p.w = fmaf(m, w.w, p.w);
        }
        p = f4add(p, f4shfl_xor(p, 32));             // combine k-chunk pairs within wave
        if (lane < 32) sRed[wave * 32 + lp] = p;
        __syncthreads();
        if (t < 32) {
            float4 z = f4add(f4add(sRed[t], sRed[32 + t]),
                             f4add(sRed[64 + t], sRed[96 + t]));
            sC[4 * t + 0] = tanhf(z.x);
            sC[4 * t + 1] = tanhf(z.y);
            sC[4 * t + 2] = tanhf(z.z);
            sC[4 * t + 3] = tanhf(z.w);
        }
        __syncthreads();

        // ---- pass 2: gate = sigmoid(x_i . c), h += gate * x_i  (re-read hits L2) ----
        float4 hacc = {0.f, 0.f, 0.f, 0.f};
        const float4 cv = ((const float4*)sC)[lp];
        for (int i = s + rg; i < e; i += 8) {
            float4 v = x4[(size_t)i * 32 + lp];
            float d = v.x * cv.x + v.y * cv.y + v.z * cv.z + v.w * cv.w;
            d += __shfl_xor(d, 16, 64);              // reduce across the 32-lane row group
            d += __shfl_xor(d,  8, 64);
            d += __shfl_xor(d,  4, 64);
            d += __shfl_xor(d,  2, 64);
            d += __shfl_xor(d,  1, 64);
            const float g = 1.0f / (1.0f + __expf(-d));
            hacc.x = fmaf(g, v.x, hacc.x);
            hacc.y = fmaf(g, v.y, hacc.y);
            hacc.z = fmaf(g, v.z, hacc.z);
            hacc.w = fmaf(g, v.w, hacc.w);
        }
        hacc = f4add(hacc, f4shfl_xor(hacc, 32));
        if (lane < 32) sRed[wave * 32 + lp] = hacc;
        __syncthreads();
        if (t < 32) {
            float4 h = f4add(f4add(sRed[t], sRed[32 + t]),
                             f4add(sRed[64 + t], sRed[96 + t]));
            ((float4*)out)[(size_t)b * 32 + t] = h;  // every b written, incl. empty segs
        }
        __syncthreads();                              // protect sRed for next segment
    }
}

extern "C" void kernel_launch(void* const* d_in, const int* in_sizes, int n_in,
                              void* d_out, int out_size, void* d_ws, size_t ws_size,
                              hipStream_t stream) {
    const float* x     = (const float*)d_in[0];
    const float* W     = (const float*)d_in[1];
    const int*   batch = (const int*)d_in[2];
    float*       out   = (float*)d_out;

    const int N = in_sizes[0] / C;   // 2,000,000
    const int B = out_size / C;      // 50,000 (avoid reading the scalar input)

    const int grid = (B + SEGS - 1) / SEGS;
    hipLaunchKernelGGL(cba_fused_kernel, dim3(grid), dim3(BLK), 0, stream,
                       x, W, batch, out, N, B);
}